// Round 4
// baseline (258.313 us; speedup 1.0000x reference)
//
#include <hip/hip_runtime.h>

#define HW    96
#define NPIX  9216        // 96*96
#define NCH   64          // C
#define INNER 3
#define NDIL  3
#define BB    2           // batch

typedef __attribute__((ext_vector_type(8))) short short8;            // 8 bf16
typedef __attribute__((ext_vector_type(8))) unsigned short ushort8;  // 8 bf16 raw
typedef __attribute__((ext_vector_type(4))) float f32x4;

__device__ __forceinline__ ushort f2bf_rne(float f) {
    unsigned u = __float_as_uint(f);
    u += 0x7fffu + ((u >> 16) & 1u);
    return (ushort)(u >> 16);
}
__device__ __forceinline__ float bf2f(ushort u) {
    return __uint_as_float((unsigned)u << 16);
}
// pack hi16(a),hi16(b) -> dword {bf16(b), bf16(a)<<16} (trunc round; ratio-safe for P)
__device__ __forceinline__ unsigned pack_bf(float lo, float hi) {
    return __builtin_amdgcn_perm(__float_as_uint(hi), __float_as_uint(lo), 0x07060302u);
}

// ---------------------------------------------------------------------------
// Kernel 1: x_red = 1x1 conv (64 -> 3 channels)
// ---------------------------------------------------------------------------
__global__ void k_reduce(const float* __restrict__ x, const float* __restrict__ w_red,
                         const float* __restrict__ b_red, float* __restrict__ xred) {
    int pix = blockIdx.x * blockDim.x + threadIdx.x;
    if (pix >= BB * NPIX) return;
    int b = pix / NPIX, n = pix % NPIX;
    float a0 = b_red[0], a1 = b_red[1], a2 = b_red[2];
    const float* xb = x + (size_t)b * NCH * NPIX + n;
    #pragma unroll
    for (int c = 0; c < NCH; ++c) {
        float xv = xb[(size_t)c * NPIX];
        a0 = fmaf(w_red[0 * NCH + c], xv, a0);
        a1 = fmaf(w_red[1 * NCH + c], xv, a1);
        a2 = fmaf(w_red[2 * NCH + c], xv, a2);
    }
    float* xr = xred + (size_t)b * INNER * NPIX + n;
    xr[0 * NPIX] = a0; xr[1 * NPIX] = a1; xr[2 * NPIX] = a2;
}

// ---------------------------------------------------------------------------
// Kernel 2 (lane=channel): wave = 1 pixel, lane = output channel.
// Emits tokens bf16 in both layouts: tok[b][n][c], tokT[b][c][n].
// ---------------------------------------------------------------------------
__global__ __launch_bounds__(256, 2) void
k_tokens(const float* __restrict__ xred,
         const float* __restrict__ w_dil, const float* __restrict__ b_dil,
         const float* __restrict__ w_fuse, const float* __restrict__ b_fuse,
         ushort* __restrict__ tok, ushort* __restrict__ tokT) {
    __shared__ float wfT[54 * NCH];        // [j][c], 13.8 KB
    __shared__ ushort tt[NCH * 4];         // transpose buffer: [c][local_pix]
    for (int i = threadIdx.x; i < 54 * NCH; i += 256) {
        int c = i / 54, j = i % 54;        // w_fuse is [C][54]
        wfT[j * NCH + c] = w_fuse[i];
    }
    __syncthreads();

    int wv = threadIdx.x >> 6, lane = threadIdx.x & 63;
    int pix = blockIdx.x * 4 + wv;         // 4 pixels per block
    int b = pix / NPIX, n = pix % NPIX;
    int h = n / HW, w = n % HW;
    const float* xr = xred + (size_t)b * INNER * NPIX;

    float tf[6][INNER];
    #pragma unroll
    for (int o = 0; o < INNER; ++o) {
        const float* xo = xr + o * NPIX;
        tf[0][o] = xo[h * HW + w];
        tf[1][o] = xo[h * HW + (HW - 1 - w)];
        tf[2][o] = xo[(HW - 1 - h) * HW + w];
        tf[3][o] = xo[w * HW + (HW - 1 - h)];
        tf[4][o] = xo[(HW - 1 - h) * HW + (HW - 1 - w)];
        tf[5][o] = xo[(HW - 1 - w) * HW + h];
    }

    float co[NDIL][INNER];
    #pragma unroll
    for (int i = 0; i < NDIL; ++i) {
        int d = i + 1;
        #pragma unroll
        for (int o = 0; o < INNER; ++o) co[i][o] = b_dil[i * INNER + o];
        #pragma unroll
        for (int ci = 0; ci < INNER; ++ci) {
            const float* xo = xr + ci * NPIX;
            #pragma unroll
            for (int kh = 0; kh < 3; ++kh) {
                int hh = h + (kh - 1) * d;
                #pragma unroll
                for (int kw = 0; kw < 3; ++kw) {
                    int ww = w + (kw - 1) * d;
                    float v = ((unsigned)hh < HW && (unsigned)ww < HW) ? xo[hh * HW + ww] : 0.f;
                    #pragma unroll
                    for (int o = 0; o < INNER; ++o)
                        co[i][o] = fmaf(w_dil[((i * INNER + o) * INNER + ci) * 9 + kh * 3 + kw],
                                        v, co[i][o]);
                }
            }
        }
    }

    float f[54];
    #pragma unroll
    for (int i = 0; i < NDIL; ++i)
        #pragma unroll
        for (int t = 0; t < 6; ++t)
            #pragma unroll
            for (int o = 0; o < INNER; ++o)
                f[(i * 6 + t) * INNER + o] = co[i][o] * tf[t][o];

    float acc = b_fuse[lane];
    #pragma unroll
    for (int j = 0; j < 54; ++j) acc = fmaf(wfT[j * NCH + lane], f[j], acc);

    ushort bfv = f2bf_rne(acc);
    tok[((size_t)b * NPIX + n) * NCH + lane] = bfv;
    tt[lane * 4 + wv] = bfv;
    __syncthreads();
    if (threadIdx.x < NCH) {
        int c = threadIdx.x;
        int n0 = (blockIdx.x * 4) % NPIX;
        int b0 = (blockIdx.x * 4) / NPIX;
        *(ushort4*)&tokT[((size_t)b0 * NCH + c) * NPIX + n0] = *(const ushort4*)&tt[c * 4];
    }
}

// ---------------------------------------------------------------------------
// Kernel 3: MFMA flash attention partials (bf16 16x16x32), transposed form.
// No K/V LDS staging, no barriers: A-fragments of S^T (keys) read straight
// from tok, A-fragments of O^T (V^T) from tokT (L1/L2 resident, 4.7 MB).
// 32-key half-tiles: S liveness 32 VGPR; per-wave P^T LDS tile 4 KB (XOR-
// swizzled 8-ushort chunks). 4 waves/wg x 64 q/wave; key range split P ways.
// exp2 domain (0.125*log2e folded into Q). pacc partials stored bf16.
// ---------------------------------------------------------------------------
__global__ __launch_bounds__(256, 3) void
k_attn(const ushort* __restrict__ tok, const ushort* __restrict__ tokT,
       float* __restrict__ pm, float* __restrict__ pl, ushort* __restrict__ pacc,
       int P, int KP) {
    __shared__ ushort pt[4][64 * 32];   // per-wave P^T [q][32key], 16 KB total

    const int QW = NPIX / 256;          // 36 query chunks per batch
    int bid = blockIdx.x;
    int qc = bid % QW; int rest = bid / QW;
    int p = rest % P;  int b = rest / P;
    int tid = threadIdx.x;
    int wv = tid >> 6, lane = tid & 63;
    int quad = lane >> 4, l15 = lane & 15;

    const ushort* tb  = tok  + (size_t)b * NPIX * NCH;
    const ushort* tbT = tokT + (size_t)b * NCH * NPIX;
    int qwave = qc * 256 + wv * 64;

    // Q fragments: B operand of S^T (lane n=l15, k=quad*8+j+32kc); scale folded.
    short8 qf[4][2];
    const float scale = 0.125f * 1.44269504088896340736f;  // 1/sqrt(C) * log2(e)
    #pragma unroll
    for (int n = 0; n < 4; ++n) {
        const ushort* qr = tb + (size_t)(qwave + 16 * n + l15) * NCH + quad * 8;
        #pragma unroll
        for (int kc = 0; kc < 2; ++kc) {
            ushort8 raw = *(const ushort8*)(qr + 32 * kc);
            short8 f;
            #pragma unroll
            for (int e = 0; e < 8; ++e) f[e] = (short)f2bf_rne(bf2f(raw[e]) * scale);
            qf[n][kc] = f;
        }
    }

    f32x4 O[4][4];                      // O^T acc: D[c=16m+quad*4+reg][q=16n+l15]
    #pragma unroll
    for (int m = 0; m < 4; ++m)
        #pragma unroll
        for (int n = 0; n < 4; ++n) O[m][n] = (f32x4){0.f, 0.f, 0.f, 0.f};
    float mrun[4], lrun[4];
    #pragma unroll
    for (int n = 0; n < 4; ++n) { mrun[n] = -1e30f; lrun[n] = 0.f; }

    int k0 = p * KP;
    for (int kb = 0; kb < KP; kb += 32) {
        int kbase = k0 + kb;

        // S^T half-tile = K(32 keys) · Q^T : D[key][q]
        f32x4 S[2][4];
        #pragma unroll
        for (int m = 0; m < 2; ++m)
            #pragma unroll
            for (int n = 0; n < 4; ++n) S[m][n] = (f32x4){0.f, 0.f, 0.f, 0.f};
        #pragma unroll
        for (int m = 0; m < 2; ++m) {
            const ushort* kr = tb + (size_t)(kbase + 16 * m + l15) * NCH + quad * 8;
            #pragma unroll
            for (int kc = 0; kc < 2; ++kc) {
                short8 kf = *(const short8*)(kr + 32 * kc);
                #pragma unroll
                for (int n = 0; n < 4; ++n)
                    S[m][n] = __builtin_amdgcn_mfma_f32_16x16x32_bf16(kf, qf[n][kc],
                                                                      S[m][n], 0, 0, 0);
            }
        }

        // V^T fragments for this half-tile (A[ch][key]) straight from tokT
        short8 vf[4];
        #pragma unroll
        for (int mc = 0; mc < 4; ++mc)
            vf[mc] = *(const short8*)(tbT + (size_t)(16 * mc + l15) * NPIX + kbase + quad * 8);

        // online softmax per query col (per-lane scalar over 32 keys)
        #pragma unroll
        for (int n = 0; n < 4; ++n) {
            float tmax = fmaxf(fmaxf(fmaxf(S[0][n][0], S[0][n][1]), fmaxf(S[0][n][2], S[0][n][3])),
                               fmaxf(fmaxf(S[1][n][0], S[1][n][1]), fmaxf(S[1][n][2], S[1][n][3])));
            tmax = fmaxf(tmax, __shfl_xor(tmax, 16, 64));
            tmax = fmaxf(tmax, __shfl_xor(tmax, 32, 64));
            float mn = fmaxf(mrun[n], tmax);
            float alpha = __builtin_amdgcn_exp2f(mrun[n] - mn);
            mrun[n] = mn;
            lrun[n] *= alpha;
            #pragma unroll
            for (int m = 0; m < 4; ++m) {
                O[m][n][0] *= alpha; O[m][n][1] *= alpha;
                O[m][n][2] *= alpha; O[m][n][3] *= alpha;
            }
            int q = 16 * n + l15;
            #pragma unroll
            for (int m = 0; m < 2; ++m) {
                float p0 = __builtin_amdgcn_exp2f(S[m][n][0] - mn);
                float p1 = __builtin_amdgcn_exp2f(S[m][n][1] - mn);
                float p2 = __builtin_amdgcn_exp2f(S[m][n][2] - mn);
                float p3 = __builtin_amdgcn_exp2f(S[m][n][3] - mn);
                lrun[n] += (p0 + p1) + (p2 + p3);
                uint2 wd = make_uint2(pack_bf(p0, p1), pack_bf(p2, p3));
                int cs = (2 * m + (quad >> 1)) ^ (q & 3);      // keys 16m+quad*4..+3
                *(uint2*)&pt[wv][q * 32 + cs * 8 + (quad & 1) * 4] = wd;
            }
        }

        // O^T += V^T·P^T (K=32): A=vf, B from pt (lane n=q, k=key=quad*8+j)
        #pragma unroll
        for (int n = 0; n < 4; ++n) {
            int q = 16 * n + l15;
            short8 bfr = *(const short8*)&pt[wv][q * 32 + (quad ^ (q & 3)) * 8];
            #pragma unroll
            for (int mc = 0; mc < 4; ++mc)
                O[mc][n] = __builtin_amdgcn_mfma_f32_16x16x32_bf16(vf[mc], bfr,
                                                                   O[mc][n], 0, 0, 0);
        }
    }

    #pragma unroll
    for (int n = 0; n < 4; ++n) {       // disjoint key subsets per quad
        lrun[n] += __shfl_xor(lrun[n], 16, 64);
        lrun[n] += __shfl_xor(lrun[n], 32, 64);
    }
    size_t bpb = ((size_t)b * P + p) * NPIX;
    if (quad == 0) {
        #pragma unroll
        for (int n = 0; n < 4; ++n) {
            int qg = qwave + 16 * n + l15;
            pm[bpb + qg] = mrun[n];
            pl[bpb + qg] = lrun[n];
        }
    }
    #pragma unroll
    for (int n = 0; n < 4; ++n) {
        int qg = qwave + 16 * n + l15;
        ushort* dst = pacc + (bpb + qg) * NCH;
        #pragma unroll
        for (int m = 0; m < 4; ++m) {
            uint2 wd = make_uint2(
                __builtin_amdgcn_perm(__float_as_uint(O[m][n][1]) + 0x8000u,
                                      __float_as_uint(O[m][n][0]) + 0x8000u, 0x07060302u),
                __builtin_amdgcn_perm(__float_as_uint(O[m][n][3]) + 0x8000u,
                                      __float_as_uint(O[m][n][2]) + 0x8000u, 0x07060302u));
            *(uint2*)(dst + 16 * m + quad * 4) = wd;
        }
    }
}

// ---------------------------------------------------------------------------
// Kernel 4: merge P partials (exp2 domain) + residual, 4-way channel split.
// pacc is bf16. out = x + 0.2*attn (NCHW).
// ---------------------------------------------------------------------------
__global__ void k_combine(const float* __restrict__ x, const float* __restrict__ pm,
                          const float* __restrict__ pl, const ushort* __restrict__ pacc,
                          float* __restrict__ out, int P) {
    int gid = blockIdx.x * blockDim.x + threadIdx.x;
    if (gid >= BB * NPIX * 4) return;
    int pix = gid >> 2, cq = gid & 3;
    int b = pix / NPIX, n = pix % NPIX;
    int c0 = cq * 16;
    float M = -1e30f;
    for (int p = 0; p < P; ++p) M = fmaxf(M, pm[((size_t)b * P + p) * NPIX + n]);
    float L = 0.f;
    float o[16];
    #pragma unroll
    for (int i = 0; i < 16; ++i) o[i] = 0.f;
    for (int p = 0; p < P; ++p) {
        size_t base = ((size_t)b * P + p) * NPIX + n;
        float fct = __builtin_amdgcn_exp2f(pm[base] - M);
        L += pl[base] * fct;
        const ushort8* pa = (const ushort8*)(pacc + base * NCH + c0);
        #pragma unroll
        for (int v = 0; v < 2; ++v) {
            ushort8 t = pa[v];
            #pragma unroll
            for (int e = 0; e < 8; ++e)
                o[8 * v + e] = fmaf(fct, bf2f(t[e]), o[8 * v + e]);
        }
    }
    float inv = 0.2f / L;
    const float* xb = x + ((size_t)b * NCH + c0) * NPIX + n;
    float* ob = out + ((size_t)b * NCH + c0) * NPIX + n;
    #pragma unroll
    for (int i = 0; i < 16; ++i)
        ob[(size_t)i * NPIX] = fmaf(inv, o[i], xb[(size_t)i * NPIX]);
}

// ---------------------------------------------------------------------------
extern "C" void kernel_launch(void* const* d_in, const int* in_sizes, int n_in,
                              void* d_out, int out_size, void* d_ws, size_t ws_size,
                              hipStream_t stream) {
    const float* x      = (const float*)d_in[0];
    const float* w_red  = (const float*)d_in[1];
    const float* b_red  = (const float*)d_in[2];
    const float* w_dil  = (const float*)d_in[3];
    const float* b_dil  = (const float*)d_in[4];
    const float* w_fuse = (const float*)d_in[5];
    const float* b_fuse = (const float*)d_in[6];
    float* out = (float*)d_out;

    // ws layout: xred f32 | tok bf16 | tokT bf16 | pm f32 | pl f32 | pacc bf16
    const size_t XRED_N = (size_t)BB * INNER * NPIX;
    const size_t TOK_N  = (size_t)BB * NPIX * NCH;
    const size_t HEAD_B = XRED_N * 4 + 2 * TOK_N * 2;
    // P must divide 144 (=NPIX/64). P=9 -> 648 blocks = one full residency
    // round at 3 blocks/CU under launch_bounds(256,3).
    int P = 0;
    const int cands[6] = {9, 8, 6, 4, 2, 1};
    for (int ci = 0; ci < 6; ++ci) {
        int cp = cands[ci];
        size_t need = HEAD_B + (size_t)BB * cp * NPIX * (4 + 4 + NCH * 2);
        if (ws_size >= need) { P = cp; break; }
    }
    if (P == 0) return;

    float*  xred = (float*)d_ws;
    ushort* tok  = (ushort*)(xred + XRED_N);
    ushort* tokT = tok + TOK_N;
    float*  pm   = (float*)(tokT + TOK_N);
    float*  pl   = pm + (size_t)BB * P * NPIX;
    ushort* pacc = (ushort*)(pl + (size_t)BB * P * NPIX);

    k_reduce <<<(BB * NPIX + 255) / 256, 256, 0, stream>>>(x, w_red, b_red, xred);
    k_tokens <<<BB * NPIX / 4, 256, 0, stream>>>(xred, w_dil, b_dil, w_fuse, b_fuse,
                                                 tok, tokT);
    k_attn   <<<BB * P * (NPIX / 256), 256, 0, stream>>>(tok, tokT, pm, pl, pacc,
                                                         P, NPIX / P);
    k_combine<<<(BB * NPIX * 4 + 255) / 256, 256, 0, stream>>>(x, pm, pl, pacc, out, P);
}